// Round 1
// baseline (108.159 us; speedup 1.0000x reference)
//
#include <hip/hip_runtime.h>
#include <cstdint>
#include <cstddef>

typedef __attribute__((ext_vector_type(4))) short short4v;
typedef __attribute__((ext_vector_type(8))) short short8v;
typedef __attribute__((ext_vector_type(4))) float floatx4;

#define LIN 568   // weight row length: 1 + 9*63
#define KP  576   // padded GEMM K: 9 taps * 64 channels (c=0 weight zeroed)

__device__ __forceinline__ short f32_to_bf16(float f) {
  unsigned u = __builtin_bit_cast(unsigned, f);
  u += 0x7fffu + ((u >> 16) & 1u);   // round-to-nearest-even (inputs are finite)
  return (short)(u >> 16);
}
__device__ __forceinline__ float bf16_to_f32(short s) {
  unsigned u = ((unsigned)(unsigned short)s) << 16;
  return __builtin_bit_cast(float, u);
}

// Repack weight[64][568] (fp32) -> Wbt[64][576] (bf16), k = tap*64 + c,
// with c==0 column zeroed (time feature handled in epilogue as rank-1).
__global__ void prep_weight(const float* __restrict__ w, short* __restrict__ wbt) {
  int i = blockIdx.x * 256 + threadIdx.x;
  if (i >= 64 * KP) return;
  int n = i / KP;
  int k = i - n * KP;
  int tap = k >> 6;
  int c = k & 63;
  float v = (c == 0) ? 0.0f : w[n * LIN + 1 + tap * 63 + (c - 1)];
  wbt[i] = f32_to_bf16(v);
}

// Block: 512 threads = 8 waves. Computes 2 output rows (128 pixels) x 65 ch.
// x-tile: rows h0-1..h0+2, cols -1..64, 64 ch (bf16, ch-stride 72).
// Weight: streamed per-tap (9 slabs of 64n x 64k) through one LDS slab.
__launch_bounds__(512, 6)
__global__ void lconv_main(const float* __restrict__ x, const float* __restrict__ w,
                           const float* __restrict__ bias, const short* __restrict__ wbt,
                           float* __restrict__ out) {
  __shared__ short xt[4 * 66 * 72];     // 38016 B
  __shared__ short wslab[64 * 72];      //  9216 B
  __shared__ float tres[128];           //   512 B

  const int tid = threadIdx.x;
  const int bb = blockIdx.x >> 5;          // batch 0..31
  const int h0 = (blockIdx.x & 31) << 1;   // first output row of the strip

  const float* xb = x + (size_t)bb * (64 * 64 * 64);

  // ---- stage x rows h0-1 .. h0+2 into xt cols 1..64 (fp32 -> bf16) ----
#pragma unroll
  for (int i = 0; i < 8; ++i) {
    int idx = i * 512 + tid;       // 0..4095
    int row = idx >> 10;           // 0..3
    int rem = idx & 1023;
    int col = rem >> 4;            // 0..63
    int ch4 = (rem & 15) << 2;     // 0,4,..,60
    int h = h0 - 1 + row;
    float4 v = make_float4(0.f, 0.f, 0.f, 0.f);
    if ((unsigned)h < 64u) v = *(const float4*)(xb + (((h * 64 + col) * 64) + ch4));
    short4v o;
    o.x = f32_to_bf16(v.x); o.y = f32_to_bf16(v.y);
    o.z = f32_to_bf16(v.z); o.w = f32_to_bf16(v.w);
    *(short4v*)&xt[(row * 66 + col + 1) * 72 + ch4] = o;
  }
  // zero the spatial-pad cols 0 and 65
  if (tid < 128) {
    int r = tid >> 5;            // 0..3
    int cc = (tid >> 4) & 1;     // 0 -> col 0, 1 -> col 65
    int ch4 = (tid & 15) << 2;
    short4v z = {0, 0, 0, 0};
    *(short4v*)&xt[(r * 66 + cc * 65) * 72 + ch4] = z;
  }
  __syncthreads();

  // ---- per-pixel time feature t_res = sqrt(sum max(x0,1)^2 - 8) ----
  if (tid < 128) {
    int pr = tid >> 6, pc = tid & 63;
    float ss = 0.f;
#pragma unroll
    for (int dh = 0; dh < 3; ++dh)
#pragma unroll
      for (int dw = 0; dw < 3; ++dw) {
        float tv = bf16_to_f32(xt[((pr + dh) * 66 + pc + dw) * 72]);
        tv = fmaxf(tv, 1.0f);
        ss += tv * tv;
      }
    tres[tid] = sqrtf(ss - 8.0f);
  }

  const int lane = tid & 63;
  const int l15 = lane & 15;
  const int q = lane >> 4;
  const int wv = tid >> 6;             // wave id = m-block id (0..7)
  const int pA = wv * 16 + l15;        // A-operand pixel (m = lane&15)
  const int prA = pA >> 6;
  const int pcA = pA & 63;

  floatx4 acc0 = {0.f, 0.f, 0.f, 0.f};
  floatx4 acc1 = acc0, acc2 = acc0, acc3 = acc0;

  const int wn = tid >> 3;             // 0..63 : weight n row
  const int wpart = (tid & 7) << 3;    // 0..56 : k offset within slab

#pragma unroll
  for (int s = 0; s < 9; ++s) {
    // stage weight slab for tap s: Wbt[n][s*64 .. s*64+63] -> wslab[n][0..63]
    short8v wv8 = *(const short8v*)(wbt + wn * KP + s * 64 + wpart);
    *(short8v*)&wslab[wn * 72 + wpart] = wv8;
    __syncthreads();

    const int kh = s / 3, kw = s % 3;
    const short* abase = &xt[((prA + kh) * 66 + (pcA + kw)) * 72];
#pragma unroll
    for (int half = 0; half < 2; ++half) {
      short8v af = *(const short8v*)(abase + half * 32 + q * 8);
      const short* bbase = &wslab[l15 * 72 + half * 32 + q * 8];
      short8v b0 = *(const short8v*)(bbase + 0 * 16 * 72);
      short8v b1 = *(const short8v*)(bbase + 1 * 16 * 72);
      short8v b2 = *(const short8v*)(bbase + 2 * 16 * 72);
      short8v b3 = *(const short8v*)(bbase + 3 * 16 * 72);
      acc0 = __builtin_amdgcn_mfma_f32_16x16x32_bf16(af, b0, acc0, 0, 0, 0);
      acc1 = __builtin_amdgcn_mfma_f32_16x16x32_bf16(af, b1, acc1, 0, 0, 0);
      acc2 = __builtin_amdgcn_mfma_f32_16x16x32_bf16(af, b2, acc2, 0, 0, 0);
      acc3 = __builtin_amdgcn_mfma_f32_16x16x32_bf16(af, b3, acc3, 0, 0, 0);
    }
    __syncthreads();   // protect wslab before next tap's staging
  }

  // ---- epilogue: bias + rank-1 time term, Lorentz norm, store ----
  float bj[4], w0j[4];
#pragma unroll
  for (int j = 0; j < 4; ++j) {
    int n = j * 16 + l15;
    bj[j] = bias[n];
    w0j[j] = w[n * LIN];   // weight[:,0] in fp32
  }
#pragma unroll
  for (int r = 0; r < 4; ++r) {
    int p = wv * 16 + q * 4 + r;       // C/D row m = quad*4 + reg
    float tr = tres[p];
    float v0 = acc0[r] + bj[0] + tr * w0j[0];
    float v1 = acc1[r] + bj[1] + tr * w0j[1];
    float v2 = acc2[r] + bj[2] + tr * w0j[2];
    float v3 = acc3[r] + bj[3] + tr * w0j[3];
    float ss = v0 * v0 + v1 * v1 + v2 * v2 + v3 * v3;
    ss += __shfl_xor(ss, 1);
    ss += __shfl_xor(ss, 2);
    ss += __shfl_xor(ss, 4);
    ss += __shfl_xor(ss, 8);
    int h = h0 + (p >> 6);
    int wc = p & 63;
    float* ob = out + (size_t)((bb * 64 + h) * 64 + wc) * 65;
    if (l15 == 0) ob[0] = sqrtf(ss + 1.0f);
    ob[1 + l15]  = v0;
    ob[17 + l15] = v1;
    ob[33 + l15] = v2;
    ob[49 + l15] = v3;
  }
}

extern "C" void kernel_launch(void* const* d_in, const int* in_sizes, int n_in,
                              void* d_out, int out_size, void* d_ws, size_t ws_size,
                              hipStream_t stream) {
  const float* x = (const float*)d_in[0];
  const float* w = (const float*)d_in[1];
  const float* b = (const float*)d_in[2];
  float* out = (float*)d_out;
  short* wbt = (short*)d_ws;   // 64*576 bf16 = 73728 B of scratch

  prep_weight<<<(64 * KP + 255) / 256, 256, 0, stream>>>(w, wbt);
  lconv_main<<<32 * 32, 512, 0, stream>>>(x, w, b, wbt, out);
}

// Round 2
// 98.875 us; speedup vs baseline: 1.0939x; 1.0939x over previous
//
#include <hip/hip_runtime.h>
#include <cstdint>
#include <cstddef>

typedef __attribute__((ext_vector_type(4))) short short4v;
typedef __attribute__((ext_vector_type(8))) short short8v;
typedef __attribute__((ext_vector_type(4))) float floatx4;

#define LIN 568   // weight row length: 1 + 9*63

__device__ __forceinline__ short f32_to_bf16(float f) {
  unsigned u = __builtin_bit_cast(unsigned, f);
  u += 0x7fffu + ((u >> 16) & 1u);   // RNE (inputs finite)
  return (short)(u >> 16);
}
__device__ __forceinline__ float bf16_to_f32(short s) {
  return __builtin_bit_cast(float, ((unsigned)(unsigned short)s) << 16);
}

// Pack weight into MFMA-B-fragment-major order (bf16):
//   wfragg[step*2048 + nb*512 + lane*8 + j]
//     = W[n = nb*16 + (lane&15)][k = tap*64 + half*32 + (lane>>4)*8 + j]
// where step = tap*2 + half, and the k%64==0 (c==0) column is zeroed
// (time feature folded in as a rank-1 epilogue term).
__global__ void prep_weight(const float* __restrict__ w, short* __restrict__ wfragg) {
  int i = blockIdx.x * 256 + threadIdx.x;   // 0 .. 36863
  if (i >= 9 * 2 * 4 * 64 * 8) return;
  int j    = i & 7;
  int lane = (i >> 3) & 63;
  int nb   = (i >> 9) & 3;
  int half = (i >> 11) & 1;
  int tap  = i >> 12;
  int n = nb * 16 + (lane & 15);
  int c = half * 32 + ((lane >> 4) << 3) + j;
  float v = (c == 0) ? 0.0f : w[n * LIN + 1 + tap * 63 + (c - 1)];
  wfragg[i] = f32_to_bf16(v);
}

// Block: 256 threads = 4 waves. Strip of 4 output rows (256 px) x 65 out-ch.
// Each wave: 1 row = 64 px = 4 m-blocks x 4 n-blocks of 16x16x32 bf16 MFMA.
// ONE barrier per block; K-loop reads A from LDS, B from global (L2-resident
// fragment-packed weight) with distance-2 register prefetch.
__launch_bounds__(256, 2)
__global__ void lconv_main(const float* __restrict__ x, const float* __restrict__ w,
                           const float* __restrict__ bias, const short* __restrict__ wfragg,
                           float* __restrict__ out) {
  __shared__ short xt[6 * 66 * 72];   // 57024 B : rows h0-1..h0+4, cols -1..64, ch stride 72
  __shared__ float tres[256];

  const int tid = threadIdx.x;
  const int bb = blockIdx.x >> 4;          // batch 0..31
  const int h0 = (blockIdx.x & 15) << 2;   // first output row of 4-row strip
  const float* xb = x + (size_t)bb * (64 * 64 * 64);

  // ---- stage x rows h0-1 .. h0+4 into xt cols 1..64 (fp32 -> bf16, b128 writes) ----
#pragma unroll
  for (int i = 0; i < 12; ++i) {
    int idx = i * 256 + tid;       // 0..3071 over 6 rows x 64 cols x 8 ch8-groups
    int row = idx >> 9;            // 0..5
    int rem = idx & 511;
    int col = rem >> 3;            // 0..63
    int ch8 = (rem & 7) << 3;      // 0,8,..,56
    int h = h0 - 1 + row;
    float4 v0 = {0.f, 0.f, 0.f, 0.f}, v1 = {0.f, 0.f, 0.f, 0.f};
    if ((unsigned)h < 64u) {
      const float* p = xb + ((h * 64 + col) * 64 + ch8);
      v0 = *(const float4*)p;
      v1 = *(const float4*)(p + 4);
    }
    short8v o;
    o[0] = f32_to_bf16(v0.x); o[1] = f32_to_bf16(v0.y);
    o[2] = f32_to_bf16(v0.z); o[3] = f32_to_bf16(v0.w);
    o[4] = f32_to_bf16(v1.x); o[5] = f32_to_bf16(v1.y);
    o[6] = f32_to_bf16(v1.z); o[7] = f32_to_bf16(v1.w);
    *(short8v*)&xt[(row * 66 + col + 1) * 72 + ch8] = o;
  }
  // zero spatial-pad cols 0 and 65 (6 rows x 2 cols x 8 groups = 96 threads)
  if (tid < 96) {
    int r = tid >> 4;              // 0..5
    int cc = (tid >> 3) & 1;       // col 0 or 65
    int ch8 = (tid & 7) << 3;
    short8v z = {0, 0, 0, 0, 0, 0, 0, 0};
    *(short8v*)&xt[(r * 66 + cc * 65) * 72 + ch8] = z;
  }
  __syncthreads();   // the only block-wide barrier

  // ---- per-pixel time feature: t_res = sqrt(sum_taps max(x0,1)^2 - 8) ----
  {
    int pr = tid >> 6, pc = tid & 63;   // pixel p = tid (row pr of strip)
    float ss = 0.f;
#pragma unroll
    for (int dh = 0; dh < 3; ++dh)
#pragma unroll
      for (int dw = 0; dw < 3; ++dw) {
        float tv = bf16_to_f32(xt[((pr + dh) * 66 + pc + dw) * 72]);
        tv = fmaxf(tv, 1.0f);
        ss += tv * tv;
      }
    tres[tid] = sqrtf(ss - 8.0f);
  }

  const int lane = tid & 63;
  const int l15 = lane & 15;
  const int q = lane >> 4;
  const int wv = tid >> 6;   // wave id = strip row

  floatx4 acc[4][4];
#pragma unroll
  for (int mb = 0; mb < 4; ++mb)
#pragma unroll
    for (int nb = 0; nb < 4; ++nb) acc[mb][nb] = floatx4{0.f, 0.f, 0.f, 0.f};

  const short* wfl = wfragg + lane * 8;

  // distance-2 register prefetch of B fragments
  short8v b0[4], b1[4];
#pragma unroll
  for (int nb = 0; nb < 4; ++nb) {
    b0[nb] = *(const short8v*)(wfl + 0 * 2048 + nb * 512);
    b1[nb] = *(const short8v*)(wfl + 1 * 2048 + nb * 512);
  }

#pragma unroll
  for (int step = 0; step < 18; ++step) {
    const int tap = step >> 1, half = step & 1;
    const int kh = tap / 3, kw = tap % 3;

    short8v bn[4];
    if (step + 2 < 18) {
#pragma unroll
      for (int nb = 0; nb < 4; ++nb)
        bn[nb] = *(const short8v*)(wfl + (step + 2) * 2048 + nb * 512);
    }

    const short* ab = &xt[((wv + kh) * 66 + kw + l15) * 72 + half * 32 + q * 8];
    short8v a[4];
#pragma unroll
    for (int mb = 0; mb < 4; ++mb)
      a[mb] = *(const short8v*)(ab + mb * 16 * 72);

#pragma unroll
    for (int mb = 0; mb < 4; ++mb) {
#pragma unroll
      for (int nb = 0; nb < 4; ++nb)
        acc[mb][nb] = __builtin_amdgcn_mfma_f32_16x16x32_bf16(a[mb], b0[nb], acc[mb][nb], 0, 0, 0);
    }
#pragma unroll
    for (int nb = 0; nb < 4; ++nb) { b0[nb] = b1[nb]; b1[nb] = bn[nb]; }
  }

  // ---- epilogue: bias + rank-1 time term, Lorentz norm (16-lane butterfly), store ----
  float bj[4], w0j[4];
#pragma unroll
  for (int nb = 0; nb < 4; ++nb) {
    int n = nb * 16 + l15;
    bj[nb] = bias[n];
    w0j[nb] = w[n * LIN];   // weight[:,0] fp32
  }
#pragma unroll
  for (int mb = 0; mb < 4; ++mb) {
#pragma unroll
    for (int r = 0; r < 4; ++r) {
      int pcol = mb * 16 + q * 4 + r;      // C/D row m = quad*4 + reg
      float tr = tres[wv * 64 + pcol];
      float v0 = acc[mb][0][r] + bj[0] + tr * w0j[0];
      float v1 = acc[mb][1][r] + bj[1] + tr * w0j[1];
      float v2 = acc[mb][2][r] + bj[2] + tr * w0j[2];
      float v3 = acc[mb][3][r] + bj[3] + tr * w0j[3];
      float ss = v0 * v0 + v1 * v1 + v2 * v2 + v3 * v3;
      ss += __shfl_xor(ss, 1);
      ss += __shfl_xor(ss, 2);
      ss += __shfl_xor(ss, 4);
      ss += __shfl_xor(ss, 8);
      float* ob = out + (size_t)((bb * 64 + h0 + wv) * 64 + pcol) * 65;
      if (l15 == 0) ob[0] = sqrtf(ss + 1.0f);
      ob[1 + l15]  = v0;
      ob[17 + l15] = v1;
      ob[33 + l15] = v2;
      ob[49 + l15] = v3;
    }
  }
}

extern "C" void kernel_launch(void* const* d_in, const int* in_sizes, int n_in,
                              void* d_out, int out_size, void* d_ws, size_t ws_size,
                              hipStream_t stream) {
  const float* x = (const float*)d_in[0];
  const float* w = (const float*)d_in[1];
  const float* b = (const float*)d_in[2];
  float* out = (float*)d_out;
  short* wfragg = (short*)d_ws;   // 73728 B fragment-packed bf16 weight

  prep_weight<<<144, 256, 0, stream>>>(w, wfragg);
  lconv_main<<<32 * 16, 256, 0, stream>>>(x, w, b, wfragg, out);
}